// Round 16
// baseline (127.568 us; speedup 1.0000x reference)
//
#include <hip/hip_runtime.h>
#include <math.h>

// ---------------- constants ----------------
#define NB 16384
#define DN 64
#define ST 68            // LDS row stride (16B-aligned rows)
// output offsets (floats)
#define OFF1 491520      // data_LiDAR
#define OFF2 983040      // HSI_A
#define OFF3 1966080     // HSI_Dn
#define OFF4 1968000     // LiDAR_A
#define OFF5 2951040     // LiDAR_Dn
#define OFF6 2952960     // output
// ws offsets (floats) — SPH/DSPH rows padded to stride 64
#define SPH_OFF  0
#define SPL_OFF  1048576
#define DSPH_OFF 1064960
#define DSPL_OFF 1069056
#define DPTH_OFF 1069120
#define DPTL_OFF 1071040
#define D2H_OFF  1072960
#define D2L_OFF  1076800

typedef const __attribute__((address_space(1))) void* gas_ptr;
typedef __attribute__((address_space(3))) void* las_ptr;

__device__ __forceinline__ float wredmax(float v) {
#pragma unroll
    for (int m = 32; m; m >>= 1) v = fmaxf(v, __shfl_xor(v, m, 64));
    return v;
}
__device__ __forceinline__ float wredsum(float v) {
#pragma unroll
    for (int m = 32; m; m >>= 1) v += __shfl_xor(v, m, 64);
    return v;
}

// ---- f4-vectorized chunk loader: xrow 16B-aligned.
template<int CH>
__device__ __forceinline__ void load_chunk(const float* __restrict__ xrow, float* __restrict__ x) {
    const int NQ = CH >> 2;
#pragma unroll
    for (int q = 0; q < NQ; ++q) {
        float4 v = *(const float4*)(xrow + 4 * q);
        x[4 * q] = v.x; x[4 * q + 1] = v.y; x[4 * q + 2] = v.z; x[4 * q + 3] = v.w;
    }
#pragma unroll
    for (int j = NQ * 4; j < CH; ++j) x[j] = xrow[j];
}

// y[o] = scale*(bias[o] + sum_c W[o*RS+c]*x[c]) for o in [o0,o0+PER) ∩ [0,OUTS)
template<int INS, int RS, int PER>
__device__ __forceinline__ void dlayer4(const float* __restrict__ W,
                                        const float* __restrict__ bias,
                                        const float* __restrict__ xb,
                                        float* __restrict__ yb,
                                        const int OUTS, const int o0,
                                        const float scale)
{
    float acc[PER];
#pragma unroll
    for (int k = 0; k < PER; ++k) {
        int oc = o0 + k; oc = oc < OUTS ? oc : OUTS - 1;
        acc[k] = bias ? bias[oc] : 0.0f;
    }
#pragma unroll
    for (int c0 = 0; c0 < INS; c0 += 16) {
        const int CHv = (INS - c0) < 16 ? (INS - c0) : 16;
        float x[16];
        if (CHv == 16) load_chunk<16>(xb + c0, x);
        else if (CHv == 15) load_chunk<15>(xb + c0, x);
        else if (CHv == 14) load_chunk<14>(xb + c0, x);
        else if (CHv == 13) load_chunk<13>(xb + c0, x);
        else if (CHv == 12) load_chunk<12>(xb + c0, x);
        else {
#pragma unroll
            for (int j = 0; j < 16; ++j) if (j < CHv) x[j] = xb[c0 + j];
        }
#pragma unroll
        for (int k = 0; k < PER; ++k) {
            int oc = o0 + k; oc = oc < OUTS ? oc : OUTS - 1;
            const float* Wr = W + oc * RS + c0;
            float a = acc[k];
#pragma unroll
            for (int j = 0; j < 16; ++j) if (j < CHv) a = fmaf(Wr[j], x[j], a);
            acc[k] = a;
        }
    }
#pragma unroll
    for (int k = 0; k < PER; ++k) {
        int o = o0 + k;
        if (o < OUTS) yb[o] = acc[k] * scale;
    }
}

// y[o] = scale * sum_c W[c*CS+o]*x[c]  (transposed weights; INS mult of 16)
template<int INS, int CS, int PER>
__device__ __forceinline__ void dlayerT4(const float* __restrict__ W,
                                         const float* __restrict__ xb,
                                         float* __restrict__ yb,
                                         const int OUTS, const int o0,
                                         const float scale)
{
    float acc[PER];
#pragma unroll
    for (int k = 0; k < PER; ++k) acc[k] = 0.0f;
#pragma unroll
    for (int c0 = 0; c0 < INS; c0 += 16) {
        float x[16];
        load_chunk<16>(xb + c0, x);
#pragma unroll
        for (int j = 0; j < 16; ++j) {
            const float* Wr = W + (c0 + j) * CS + o0;
#pragma unroll
            for (int k = 0; k < PER; ++k) acc[k] = fmaf(Wr[k], x[j], acc[k]);
        }
    }
#pragma unroll
    for (int k = 0; k < PER; ++k) {
        int o = o0 + k;
        if (o < OUTS) yb[o] = acc[k] * scale;
    }
}

// exp(S - max(S)) over a 64-wide row (f4); virtual wave vw covers cols 4vw..4vw+3.
// Item rows indexed by l32 (0..31); partials P[vw*32 + l32].
__device__ __forceinline__ void softmax_exp4v(const float* __restrict__ Sb,
                                              float* __restrict__ Qb,
                                              float* __restrict__ P,
                                              const int vw, const int l32)
{
    const float4* S4 = (const float4*)Sb;
    float4 m4 = S4[0];
#pragma unroll
    for (int q = 1; q < 16; ++q) {
        float4 v = S4[q];
        m4.x = fmaxf(m4.x, v.x); m4.y = fmaxf(m4.y, v.y);
        m4.z = fmaxf(m4.z, v.z); m4.w = fmaxf(m4.w, v.w);
    }
    const float mx = fmaxf(fmaxf(m4.x, m4.y), fmaxf(m4.z, m4.w));
    float4 sv = S4[vw];
    float4 e;
    e.x = __expf(sv.x - mx); e.y = __expf(sv.y - mx);
    e.z = __expf(sv.z - mx); e.w = __expf(sv.w - mx);
    ((float4*)Qb)[vw] = e;
    P[vw * 32 + l32] = (e.x + e.y) + (e.z + e.w);
}

// 1/sum over 16 virtual-wave partials (stride 32)
__device__ __forceinline__ float inv16v(const float* __restrict__ P, const int l32)
{
    float s0 = P[l32], s1 = P[32 + l32], s2 = P[64 + l32], s3 = P[96 + l32];
#pragma unroll
    for (int g = 4; g < 16; g += 4) {
        s0 += P[g * 32 + l32];
        s1 += P[(g + 1) * 32 + l32];
        s2 += P[(g + 2) * 32 + l32];
        s3 += P[(g + 3) * 32 + l32];
    }
    return 1.0f / ((s0 + s1) + (s2 + s3));
}

// ---------------- Kernel A: patch attention (4 items/block; dict grid merged) ----------------
__global__ __launch_bounds__(256) void patch_attend_kernel(
    const float* __restrict__ patchH, const float* __restrict__ xH,
    const float* __restrict__ patchL, const float* __restrict__ xL,
    float* __restrict__ spH, float* __restrict__ spL,
    const float* __restrict__ dpH, const float* __restrict__ dxH,
    const float* __restrict__ dpL, const float* __restrict__ dxL,
    float* __restrict__ dspH, float* __restrict__ dspL)
{
    __shared__ __align__(16) float ph[4 * 3087];
    __shared__ __align__(16) float pl_[4 * 49];
    __shared__ __align__(16) float xh[4 * 63];
    __shared__ float xls[4];
    __shared__ float pw[4 * 49];

    const int tid = threadIdx.x;
    const bool isD = blockIdx.x >= (NB / 4);
    const int b0 = (isD ? (blockIdx.x - NB / 4) : blockIdx.x) * 4;
    const float* PH = isD ? dpH : patchH;
    const float* XH = isD ? dxH : xH;
    const float* PL = isD ? dpL : patchL;
    const float* XL = isD ? dxL : xL;
    float* SH = isD ? dspH : spH;
    float* SL = isD ? dspL : spL;
    {
        const float4* s4 = (const float4*)(PH + (size_t)b0 * 3087);
        float4* d4 = (float4*)ph;
        for (int i = tid; i < 3087; i += 256) {
            __builtin_amdgcn_global_load_lds((gas_ptr)(const void*)(s4 + i),
                                             (las_ptr)(void*)(d4 + i), 16, 0, 0);
        }
        if (tid < 49) ((float4*)pl_)[tid] = ((const float4*)(PL + (size_t)b0 * 49))[tid];
        if (tid >= 64 && tid < 127) ((float4*)xh)[tid - 64] = ((const float4*)(XH + (size_t)b0 * 63))[tid - 64];
        if (tid == 255) *((float4*)xls) = *((const float4*)(XL + b0));
    }
    asm volatile("s_waitcnt vmcnt(0)" ::: "memory");
    __syncthreads();

    const int w = tid >> 6, l = tid & 63;
    const float* phw = ph + w * 3087;
    const float* plw = pl_ + w * 49;
    const float* xhw = xh + w * 63;
    const float xlw = xls[w];

    float eh = -INFINITY, el = -INFINITY;
    if (l < 49) {
        float acc = 0.f;
#pragma unroll
        for (int c = 0; c < 63; ++c) {
            float t = xhw[c] - phw[c * 49 + l] + 1e-6f;
            acc = fmaf(t, t, acc);
        }
        eh = __expf(-sqrtf(acc));
        float tl = xlw - plw[l] + 1e-6f;
        el = __expf(-fabsf(tl));
    }
    float mh = wredmax(eh), ml = wredmax(el);
    float qh = (l < 49) ? __expf(eh - mh) : 0.f;
    float ql = (l < 49) ? __expf(el - ml) : 0.f;
    float sh = wredsum(qh);
    float sl = wredsum(ql);
    if (l < 49) pw[w * 49 + l] = qh / sh;
    float spl_v = wredsum((l < 49) ? plw[l] * (ql / sl) : 0.f);
    if (l == 0) SL[b0 + w] = spl_v;
    __syncthreads();
    if (l < 63) {
        float acc = 0.f;
        const float* pww = pw + w * 49;
#pragma unroll
        for (int s = 0; s < 49; ++s) acc = fmaf(phw[l * 49 + s], pww[s], acc);
        SH[(size_t)(b0 + w) * 64 + l] = acc;   // stride-64 rows (col 63 unused)
    }
}

// ---------------- Kernel C: dictionary chain (1 block, 16 waves, H+L interleaved) ----------------
__global__ __launch_bounds__(1024) void dict_chain_kernel(
    const float* __restrict__ dsph, const float* __restrict__ dspl,
    const float* __restrict__ w1_1, const float* __restrict__ b1_1,
    const float* __restrict__ w1_2, const float* __restrict__ b1_2,
    const float* __restrict__ w2_1, const float* __restrict__ b2_1,
    const float* __restrict__ w2_2, const float* __restrict__ b2_2,
    const float* __restrict__ wa2, const float* __restrict__ ba2,
    float* __restrict__ dptH, float* __restrict__ dptL,
    float* __restrict__ d2H, float* __restrict__ d2L,
    const int* __restrict__ mI, float* __restrict__ out)
{
    __shared__ __align__(16) float HA[64 * ST];
    __shared__ __align__(16) float HB[64 * ST];
    __shared__ __align__(16) float LA[64 * ST];
    __shared__ __align__(16) float LB[64 * ST];
    __shared__ float XLs[64];
    const int tid = threadIdx.x;
    const int w = __builtin_amdgcn_readfirstlane(tid >> 6);
    const int l = tid & 63;
    const float mf = (float)(*mI);
    {
        int r = tid >> 4, q = tid & 15;
        *(float4*)(HA + r * ST + 4 * q) = ((const float4*)dsph)[tid];
        if (tid < 64) XLs[tid] = dspl[tid];
    }
    __syncthreads();
    // s1: H 63->45 ; L 1->15
    dlayer4<63, 63, 3>(w1_1, b1_1, HA + l * ST, HB + l * ST, 45, w * 3, 1.0f);
    dlayer4<1, 1, 1>(w2_1, b2_1, XLs + l, LA + l * ST, 15, w, 1.0f);
    __syncthreads();
    // s2: H 45->30 ; L 15->30
    dlayer4<45, 45, 2>(w1_2, b1_2, HB + l * ST, HA + l * ST, 30, w * 2, 1.0f);
    dlayer4<15, 15, 2>(w2_2, b2_2, LA + l * ST, LB + l * ST, 30, w * 2, 1.0f);
    __syncthreads();
    // dpt copies + Dn = m*Dp + s3 (wa2 30->60)
    for (int i = tid; i < 1920; i += 1024) {
        int r = i / 30, c = i - r * 30;
        dptH[i] = HA[r * ST + c];
        dptL[i] = LB[r * ST + c];
    }
    for (int i = tid; i < 1920; i += 1024) {
        int c = i >> 6, j = i & 63;
        out[OFF3 + i] = mf * HA[j * ST + c];
        out[OFF5 + i] = mf * LB[j * ST + c];
    }
    dlayer4<30, 30, 4>(wa2, ba2, HA + l * ST, HB + l * ST, 60, w * 4, 1.0f);
    dlayer4<30, 30, 4>(wa2, ba2, LB + l * ST, LA + l * ST, 60, w * 4, 1.0f);
    __syncthreads();
    for (int i = tid; i < 3840; i += 1024) {
        int r = i / 60, c = i - r * 60;
        d2H[i] = HB[r * ST + c];
        d2L[i] = LA[r * ST + c];
    }
}

// ---------------- Kernel B: per-item chain — 32 items/block, 512 threads (8 waves),
// 16 VIRTUAL 32-lane waves split outputs; ~39 KB LDS -> 3-4 blocks/CU so barrier
// stalls in one block are hidden by co-resident blocks. Momentum fused (m != 1). ----------------
__global__ __launch_bounds__(512) void chain_kernel(
    const float* __restrict__ spH, const float* __restrict__ spL,
    const float* __restrict__ dptH, const float* __restrict__ dptL,
    const float* __restrict__ d2H, const float* __restrict__ d2L,
    const float* __restrict__ w1_1, const float* __restrict__ b1_1,
    const float* __restrict__ w1_2, const float* __restrict__ b1_2,
    const float* __restrict__ w2_1, const float* __restrict__ b2_1,
    const float* __restrict__ w2_2, const float* __restrict__ b2_2,
    const float* __restrict__ wa1, const float* __restrict__ ba1,
    const float* __restrict__ wo1, const float* __restrict__ bo1,
    const float* __restrict__ wo2, const float* __restrict__ bo2,
    const int* __restrict__ mI,
    float* __restrict__ out)
{
    __shared__ __align__(16) float HA[32 * ST];
    __shared__ __align__(16) float HB[32 * ST];
    __shared__ __align__(16) float LA[32 * ST];
    __shared__ __align__(16) float LB[32 * ST];
    __shared__ float XLs[32];
    __shared__ float PH[16 * 32], PL[16 * 32];
    __shared__ float INVH[32], INVL[32];

    const int tid = threadIdx.x;
    const int vw = tid >> 5;          // virtual wave 0..15
    const int l32 = tid & 31;         // item slot 0..31
    const int b0 = blockIdx.x * 32;
    const float mf = (float)(*mI);

    {
        int r = tid >> 4, q = tid & 15;
        *(float4*)(HA + r * ST + 4 * q) = ((const float4*)(spH + (size_t)b0 * 64))[tid];
        if (tid < 32) XLs[tid] = spL[b0 + tid];
    }
    __syncthreads();

    // s1: H 63->45 ; L 1->15
    dlayer4<63, 63, 3>(w1_1, b1_1, HA + l32 * ST, HB + l32 * ST, 45, vw * 3, 1.0f);
    dlayer4<1, 1, 1>(w2_1, b2_1, XLs + l32, LA + l32 * ST, 15, vw, 1.0f);
    __syncthreads();
    // s2: H 45->30 ; L 15->30
    dlayer4<45, 45, 2>(w1_2, b1_2, HB + l32 * ST, HA + l32 * ST, 30, vw * 2, 1.0f);
    dlayer4<15, 15, 2>(w2_2, b2_2, LA + l32 * ST, LB + l32 * ST, 30, vw * 2, 1.0f);
    __syncthreads();
    // data copies + s3: 30->60 (wa1) both branches
    for (int i = tid; i < 960; i += 512) {
        int r = i / 30, c = i - r * 30;
        out[(size_t)b0 * 30 + i] = HA[r * ST + c];
        out[OFF1 + (size_t)b0 * 30 + i] = LB[r * ST + c];
    }
    dlayer4<30, 30, 4>(wa1, ba1, HA + l32 * ST, HB + l32 * ST, 60, vw * 4, 1.0f);
    dlayer4<30, 30, 4>(wa1, ba1, LB + l32 * ST, LA + l32 * ST, 60, vw * 4, 1.0f);
    __syncthreads();
    // s4: S = H1 @ D2^T (60->64) both branches
    dlayer4<60, 60, 4>(d2H, nullptr, HB + l32 * ST, HA + l32 * ST, 64, vw * 4, 1.0f);
    dlayer4<60, 60, 4>(d2L, nullptr, LA + l32 * ST, LB + l32 * ST, 64, vw * 4, 1.0f);
    __syncthreads();
    // s5: exp(S - max) both branches
    softmax_exp4v(HA + l32 * ST, HB + l32 * ST, PH, vw, l32);
    softmax_exp4v(LB + l32 * ST, LA + l32 * ST, PL, vw, l32);
    __syncthreads();
    // fused momentum update (only when m != 1): Dn += (1-m) * data^T @ A.
    if (mf != 1.0f) {
        if (tid < 32) INVH[tid] = inv16v(PH, tid);
        else if (tid < 64) INVL[tid - 32] = inv16v(PL, tid - 32);
        __syncthreads();
        const int w8 = __builtin_amdgcn_readfirstlane(tid >> 6);  // 0..7
        const int l64 = tid & 63;                                  // atom
        const bool isH = w8 < 4;
        const float* E = isH ? HB : LA;
        const float* INV = isH ? INVH : INVL;
        const float* dat = out + (isH ? 0 : OFF1) + (size_t)b0 * 30;
        float* D = out + (isH ? OFF3 : OFF5);
        const int c0 = (w8 & 3) * 8;
        float acc[8];
#pragma unroll
        for (int k = 0; k < 8; ++k) acc[k] = 0.f;
        for (int it = 0; it < 32; ++it) {
            const float a = E[it * ST + l64] * INV[it];
#pragma unroll
            for (int k = 0; k < 8; ++k) {
                int c = c0 + k; c = c < 30 ? c : 29;
                acc[k] = fmaf(dat[it * 30 + c], a, acc[k]);
            }
        }
        const float s = 1.0f - mf;
#pragma unroll
        for (int k = 0; k < 8; ++k) {
            int c = c0 + k;
            if (c < 30) atomicAdd(&D[c * 64 + l64], s * acc[k]);
        }
    }
    {
        const float invH = inv16v(PH, l32);
        const float invL = inv16v(PL, l32);
        dlayerT4<64, 30, 2>(dptH, HB + l32 * ST, HA + l32 * ST, 30, vw * 2, invH);
        dlayerT4<64, 30, 2>(dptL, LA + l32 * ST, LB + l32 * ST, 30, vw * 2, invL);
    }
    __syncthreads();
    // s8: 30->60 (wa1) both branches
    dlayer4<30, 30, 4>(wa1, ba1, HA + l32 * ST, HB + l32 * ST, 60, vw * 4, 1.0f);
    dlayer4<30, 30, 4>(wa1, ba1, LB + l32 * ST, LA + l32 * ST, 60, vw * 4, 1.0f);
    __syncthreads();
    // HSI_A / LiDAR_A copies
    for (int i = tid; i < 1920; i += 512) {
        int r = i / 60, c = i - r * 60;
        out[OFF2 + (size_t)b0 * 60 + i] = HB[r * ST + c];
        out[OFF4 + (size_t)b0 * 60 + i] = LA[r * ST + c];
    }
    // o1: 120->60 = wo1[:, :60]@A60l + wo1[:, 60:]@A60h (f4 chunked)
    {
        const int o0 = vw * 4;
        float acc[4];
#pragma unroll
        for (int k = 0; k < 4; ++k) acc[k] = (o0 + k < 60) ? bo1[o0 + k] : 0.0f;
#pragma unroll
        for (int c0 = 0; c0 < 60; c0 += 16) {
            const int CH = (60 - c0) < 16 ? (60 - c0) : 16;
            float x[16];
            if (CH == 16) load_chunk<16>(LA + l32 * ST + c0, x);
            else load_chunk<12>(LA + l32 * ST + c0, x);
#pragma unroll
            for (int k = 0; k < 4; ++k) {
                int oc = o0 + k; oc = oc < 60 ? oc : 59;
                const float* Wr = wo1 + oc * 120 + c0;
                float a = acc[k];
#pragma unroll
                for (int j = 0; j < 16; ++j) if (j < CH) a = fmaf(Wr[j], x[j], a);
                acc[k] = a;
            }
        }
#pragma unroll
        for (int c0 = 0; c0 < 60; c0 += 16) {
            const int CH = (60 - c0) < 16 ? (60 - c0) : 16;
            float x[16];
            if (CH == 16) load_chunk<16>(HB + l32 * ST + c0, x);
            else load_chunk<12>(HB + l32 * ST + c0, x);
#pragma unroll
            for (int k = 0; k < 4; ++k) {
                int oc = o0 + k; oc = oc < 60 ? oc : 59;
                const float* Wr = wo1 + oc * 120 + 60 + c0;
                float a = acc[k];
#pragma unroll
                for (int j = 0; j < 16; ++j) if (j < CH) a = fmaf(Wr[j], x[j], a);
                acc[k] = a;
            }
        }
        if (o0 < 60) {
            float4 av; av.x = acc[0]; av.y = acc[1]; av.z = acc[2]; av.w = acc[3];
            *((float4*)(HA + l32 * ST + o0)) = av;
        }
    }
    __syncthreads();
    // o2: 60->7 (virtual waves 0-6; lane = item)
    if (vw < 7) {
        float a = bo2[vw];
        const float* Wr = wo2 + vw * 60;
#pragma unroll
        for (int c0 = 0; c0 < 60; c0 += 16) {
            const int CH = (60 - c0) < 16 ? (60 - c0) : 16;
            float x[16];
            if (CH == 16) load_chunk<16>(HA + l32 * ST + c0, x);
            else load_chunk<12>(HA + l32 * ST + c0, x);
#pragma unroll
            for (int j = 0; j < 16; ++j) if (j < CH) a = fmaf(Wr[c0 + j], x[j], a);
        }
        out[OFF6 + (size_t)(b0 + l32) * 7 + vw] = a;
    }
}

extern "C" void kernel_launch(void* const* d_in, const int* in_sizes, int n_in,
                              void* d_out, int out_size, void* d_ws, size_t ws_size,
                              hipStream_t stream) {
    const float* H_HSI        = (const float*)d_in[0];
    const float* H_LiDAR      = (const float*)d_in[1];
    const float* HSI_D        = (const float*)d_in[2];
    const float* LiDAR_D      = (const float*)d_in[3];
    const float* Patch_HSI    = (const float*)d_in[4];
    const float* Patch_LiDAR  = (const float*)d_in[5];
    const float* D_Patch_HSI  = (const float*)d_in[6];
    const float* D_Patch_LiDAR= (const float*)d_in[7];
    const int*   mI           = (const int*)d_in[9];
    const float* w1_1 = (const float*)d_in[12];
    const float* b1_1 = (const float*)d_in[13];
    const float* w1_2 = (const float*)d_in[14];
    const float* b1_2 = (const float*)d_in[15];
    const float* w2_1 = (const float*)d_in[16];
    const float* b2_1 = (const float*)d_in[17];
    const float* w2_2 = (const float*)d_in[18];
    const float* b2_2 = (const float*)d_in[19];
    const float* wa1  = (const float*)d_in[20];
    const float* ba1  = (const float*)d_in[21];
    const float* wa2  = (const float*)d_in[22];
    const float* ba2  = (const float*)d_in[23];
    const float* wo1  = (const float*)d_in[24];
    const float* bo1  = (const float*)d_in[25];
    const float* wo2  = (const float*)d_in[26];
    const float* bo2  = (const float*)d_in[27];

    float* out = (float*)d_out;
    float* ws  = (float*)d_ws;

    patch_attend_kernel<<<NB / 4 + DN / 4, 256, 0, stream>>>(
        Patch_HSI, H_HSI, Patch_LiDAR, H_LiDAR, ws + SPH_OFF, ws + SPL_OFF,
        D_Patch_HSI, HSI_D, D_Patch_LiDAR, LiDAR_D, ws + DSPH_OFF, ws + DSPL_OFF);
    dict_chain_kernel<<<1, 1024, 0, stream>>>(
        ws + DSPH_OFF, ws + DSPL_OFF,
        w1_1, b1_1, w1_2, b1_2, w2_1, b2_1, w2_2, b2_2, wa2, ba2,
        ws + DPTH_OFF, ws + DPTL_OFF, ws + D2H_OFF, ws + D2L_OFF, mI, out);
    chain_kernel<<<NB / 32, 512, 0, stream>>>(
        ws + SPH_OFF, ws + SPL_OFF,
        ws + DPTH_OFF, ws + DPTL_OFF, ws + D2H_OFF, ws + D2L_OFF,
        w1_1, b1_1, w1_2, b1_2, w2_1, b2_1, w2_2, b2_2,
        wa1, ba1, wo1, bo1, wo2, bo2, mI, out);
}

// Round 17
// 83.123 us; speedup vs baseline: 1.5347x; 1.5347x over previous
//
#include <hip/hip_runtime.h>
#include <math.h>

// ---------------- constants ----------------
#define NB 16384
#define DN 64
#define ST 68            // LDS row stride (16B-aligned rows)
// output offsets (floats)
#define OFF1 491520      // data_LiDAR
#define OFF2 983040      // HSI_A
#define OFF3 1966080     // HSI_Dn
#define OFF4 1968000     // LiDAR_A
#define OFF5 2951040     // LiDAR_Dn
#define OFF6 2952960     // output
// ws offsets (floats) — SPH/DSPH rows padded to stride 64
#define SPH_OFF  0
#define SPL_OFF  1048576
#define DSPH_OFF 1064960
#define DSPL_OFF 1069056
#define DPTH_OFF 1069120
#define DPTL_OFF 1071040
#define D2H_OFF  1072960
#define D2L_OFF  1076800

typedef const __attribute__((address_space(1))) void* gas_ptr;
typedef __attribute__((address_space(3))) void* las_ptr;

__device__ __forceinline__ float wredmax(float v) {
#pragma unroll
    for (int m = 32; m; m >>= 1) v = fmaxf(v, __shfl_xor(v, m, 64));
    return v;
}
__device__ __forceinline__ float wredsum(float v) {
#pragma unroll
    for (int m = 32; m; m >>= 1) v += __shfl_xor(v, m, 64);
    return v;
}

// ---- f4-vectorized chunk loader: xrow 16B-aligned.
template<int CH>
__device__ __forceinline__ void load_chunk(const float* __restrict__ xrow, float* __restrict__ x) {
    const int NQ = CH >> 2;
#pragma unroll
    for (int q = 0; q < NQ; ++q) {
        float4 v = *(const float4*)(xrow + 4 * q);
        x[4 * q] = v.x; x[4 * q + 1] = v.y; x[4 * q + 2] = v.z; x[4 * q + 3] = v.w;
    }
#pragma unroll
    for (int j = NQ * 4; j < CH; ++j) x[j] = xrow[j];
}

// y[o] = scale*(bias[o] + sum_c W[o*RS+c]*x[c]) for o in [o0,o0+PER) ∩ [0,OUTS)
template<int INS, int RS, int PER>
__device__ __forceinline__ void dlayer4(const float* __restrict__ W,
                                        const float* __restrict__ bias,
                                        const float* __restrict__ xb,
                                        float* __restrict__ yb,
                                        const int OUTS, const int o0,
                                        const float scale)
{
    float acc[PER];
#pragma unroll
    for (int k = 0; k < PER; ++k) {
        int oc = o0 + k; oc = oc < OUTS ? oc : OUTS - 1;
        acc[k] = bias ? bias[oc] : 0.0f;
    }
#pragma unroll
    for (int c0 = 0; c0 < INS; c0 += 16) {
        const int CHv = (INS - c0) < 16 ? (INS - c0) : 16;
        float x[16];
        if (CHv == 16) load_chunk<16>(xb + c0, x);
        else if (CHv == 15) load_chunk<15>(xb + c0, x);
        else if (CHv == 14) load_chunk<14>(xb + c0, x);
        else if (CHv == 13) load_chunk<13>(xb + c0, x);
        else if (CHv == 12) load_chunk<12>(xb + c0, x);
        else {
#pragma unroll
            for (int j = 0; j < 16; ++j) if (j < CHv) x[j] = xb[c0 + j];
        }
#pragma unroll
        for (int k = 0; k < PER; ++k) {
            int oc = o0 + k; oc = oc < OUTS ? oc : OUTS - 1;
            const float* Wr = W + oc * RS + c0;
            float a = acc[k];
#pragma unroll
            for (int j = 0; j < 16; ++j) if (j < CHv) a = fmaf(Wr[j], x[j], a);
            acc[k] = a;
        }
    }
#pragma unroll
    for (int k = 0; k < PER; ++k) {
        int o = o0 + k;
        if (o < OUTS) yb[o] = acc[k] * scale;
    }
}

// y[o] = scale * sum_c W[c*CS+o]*x[c]  (transposed weights; INS mult of 16)
template<int INS, int CS, int PER>
__device__ __forceinline__ void dlayerT4(const float* __restrict__ W,
                                         const float* __restrict__ xb,
                                         float* __restrict__ yb,
                                         const int OUTS, const int o0,
                                         const float scale)
{
    float acc[PER];
#pragma unroll
    for (int k = 0; k < PER; ++k) acc[k] = 0.0f;
#pragma unroll
    for (int c0 = 0; c0 < INS; c0 += 16) {
        float x[16];
        load_chunk<16>(xb + c0, x);
#pragma unroll
        for (int j = 0; j < 16; ++j) {
            const float* Wr = W + (c0 + j) * CS + o0;
#pragma unroll
            for (int k = 0; k < PER; ++k) acc[k] = fmaf(Wr[k], x[j], acc[k]);
        }
    }
#pragma unroll
    for (int k = 0; k < PER; ++k) {
        int o = o0 + k;
        if (o < OUTS) yb[o] = acc[k] * scale;
    }
}

// exp(S - max(S)) over a 64-wide row (f4); wave w covers cols 4w..4w+3 (16 waves).
__device__ __forceinline__ void softmax_exp4(const float* __restrict__ Sb,
                                             float* __restrict__ Qb,
                                             float* __restrict__ P,
                                             const int w, const int l)
{
    const float4* S4 = (const float4*)Sb;
    float4 m4 = S4[0];
#pragma unroll
    for (int q = 1; q < 16; ++q) {
        float4 v = S4[q];
        m4.x = fmaxf(m4.x, v.x); m4.y = fmaxf(m4.y, v.y);
        m4.z = fmaxf(m4.z, v.z); m4.w = fmaxf(m4.w, v.w);
    }
    const float mx = fmaxf(fmaxf(m4.x, m4.y), fmaxf(m4.z, m4.w));
    float4 sv = S4[w];
    float4 e;
    e.x = __expf(sv.x - mx); e.y = __expf(sv.y - mx);
    e.z = __expf(sv.z - mx); e.w = __expf(sv.w - mx);
    ((float4*)Qb)[w] = e;
    P[w * 64 + l] = (e.x + e.y) + (e.z + e.w);
}

// 1/sum over 16 per-wave partials
__device__ __forceinline__ float inv16(const float* __restrict__ P, const int l)
{
    float s0 = P[l], s1 = P[64 + l], s2 = P[128 + l], s3 = P[192 + l];
#pragma unroll
    for (int g = 4; g < 16; g += 4) {
        s0 += P[g * 64 + l];
        s1 += P[(g + 1) * 64 + l];
        s2 += P[(g + 2) * 64 + l];
        s3 += P[(g + 3) * 64 + l];
    }
    return 1.0f / ((s0 + s1) + (s2 + s3));
}

// ---------------- Kernel A: patch attention (4 items/block; dict grid merged) ----------------
__global__ __launch_bounds__(256) void patch_attend_kernel(
    const float* __restrict__ patchH, const float* __restrict__ xH,
    const float* __restrict__ patchL, const float* __restrict__ xL,
    float* __restrict__ spH, float* __restrict__ spL,
    const float* __restrict__ dpH, const float* __restrict__ dxH,
    const float* __restrict__ dpL, const float* __restrict__ dxL,
    float* __restrict__ dspH, float* __restrict__ dspL)
{
    __shared__ __align__(16) float ph[4 * 3087];
    __shared__ __align__(16) float pl_[4 * 49];
    __shared__ __align__(16) float xh[4 * 63];
    __shared__ float xls[4];
    __shared__ float pw[4 * 49];

    const int tid = threadIdx.x;
    const bool isD = blockIdx.x >= (NB / 4);
    const int b0 = (isD ? (blockIdx.x - NB / 4) : blockIdx.x) * 4;
    const float* PH = isD ? dpH : patchH;
    const float* XH = isD ? dxH : xH;
    const float* PL = isD ? dpL : patchL;
    const float* XL = isD ? dxL : xL;
    float* SH = isD ? dspH : spH;
    float* SL = isD ? dspL : spL;
    {
        const float4* s4 = (const float4*)(PH + (size_t)b0 * 3087);
        float4* d4 = (float4*)ph;
        for (int i = tid; i < 3087; i += 256) {
            __builtin_amdgcn_global_load_lds((gas_ptr)(const void*)(s4 + i),
                                             (las_ptr)(void*)(d4 + i), 16, 0, 0);
        }
        if (tid < 49) ((float4*)pl_)[tid] = ((const float4*)(PL + (size_t)b0 * 49))[tid];
        if (tid >= 64 && tid < 127) ((float4*)xh)[tid - 64] = ((const float4*)(XH + (size_t)b0 * 63))[tid - 64];
        if (tid == 255) *((float4*)xls) = *((const float4*)(XL + b0));
    }
    asm volatile("s_waitcnt vmcnt(0)" ::: "memory");
    __syncthreads();

    const int w = tid >> 6, l = tid & 63;
    const float* phw = ph + w * 3087;
    const float* plw = pl_ + w * 49;
    const float* xhw = xh + w * 63;
    const float xlw = xls[w];

    float eh = -INFINITY, el = -INFINITY;
    if (l < 49) {
        float acc = 0.f;
#pragma unroll
        for (int c = 0; c < 63; ++c) {
            float t = xhw[c] - phw[c * 49 + l] + 1e-6f;
            acc = fmaf(t, t, acc);
        }
        eh = __expf(-sqrtf(acc));
        float tl = xlw - plw[l] + 1e-6f;
        el = __expf(-fabsf(tl));
    }
    float mh = wredmax(eh), ml = wredmax(el);
    float qh = (l < 49) ? __expf(eh - mh) : 0.f;
    float ql = (l < 49) ? __expf(el - ml) : 0.f;
    float sh = wredsum(qh);
    float sl = wredsum(ql);
    if (l < 49) pw[w * 49 + l] = qh / sh;
    float spl_v = wredsum((l < 49) ? plw[l] * (ql / sl) : 0.f);
    if (l == 0) SL[b0 + w] = spl_v;
    __syncthreads();
    if (l < 63) {
        float acc = 0.f;
        const float* pww = pw + w * 49;
#pragma unroll
        for (int s = 0; s < 49; ++s) acc = fmaf(phw[l * 49 + s], pww[s], acc);
        SH[(size_t)(b0 + w) * 64 + l] = acc;   // stride-64 rows (col 63 unused)
    }
}

// ---------------- Kernel C: dictionary chain (1 block, 16 waves, H+L interleaved) ----------------
__global__ __launch_bounds__(1024) void dict_chain_kernel(
    const float* __restrict__ dsph, const float* __restrict__ dspl,
    const float* __restrict__ w1_1, const float* __restrict__ b1_1,
    const float* __restrict__ w1_2, const float* __restrict__ b1_2,
    const float* __restrict__ w2_1, const float* __restrict__ b2_1,
    const float* __restrict__ w2_2, const float* __restrict__ b2_2,
    const float* __restrict__ wa2, const float* __restrict__ ba2,
    float* __restrict__ dptH, float* __restrict__ dptL,
    float* __restrict__ d2H, float* __restrict__ d2L,
    const int* __restrict__ mI, float* __restrict__ out)
{
    __shared__ __align__(16) float HA[64 * ST];
    __shared__ __align__(16) float HB[64 * ST];
    __shared__ __align__(16) float LA[64 * ST];
    __shared__ __align__(16) float LB[64 * ST];
    __shared__ float XLs[64];
    const int tid = threadIdx.x;
    const int w = __builtin_amdgcn_readfirstlane(tid >> 6);
    const int l = tid & 63;
    const float mf = (float)(*mI);
    {
        int r = tid >> 4, q = tid & 15;
        *(float4*)(HA + r * ST + 4 * q) = ((const float4*)dsph)[tid];
        if (tid < 64) XLs[tid] = dspl[tid];
    }
    __syncthreads();
    // s1: H 63->45 ; L 1->15
    dlayer4<63, 63, 3>(w1_1, b1_1, HA + l * ST, HB + l * ST, 45, w * 3, 1.0f);
    dlayer4<1, 1, 1>(w2_1, b2_1, XLs + l, LA + l * ST, 15, w, 1.0f);
    __syncthreads();
    // s2: H 45->30 ; L 15->30
    dlayer4<45, 45, 2>(w1_2, b1_2, HB + l * ST, HA + l * ST, 30, w * 2, 1.0f);
    dlayer4<15, 15, 2>(w2_2, b2_2, LA + l * ST, LB + l * ST, 30, w * 2, 1.0f);
    __syncthreads();
    // dpt copies + Dn = m*Dp + s3 (wa2 30->60)
    for (int i = tid; i < 1920; i += 1024) {
        int r = i / 30, c = i - r * 30;
        dptH[i] = HA[r * ST + c];
        dptL[i] = LB[r * ST + c];
    }
    for (int i = tid; i < 1920; i += 1024) {
        int c = i >> 6, j = i & 63;
        out[OFF3 + i] = mf * HA[j * ST + c];
        out[OFF5 + i] = mf * LB[j * ST + c];
    }
    dlayer4<30, 30, 4>(wa2, ba2, HA + l * ST, HB + l * ST, 60, w * 4, 1.0f);
    dlayer4<30, 30, 4>(wa2, ba2, LB + l * ST, LA + l * ST, 60, w * 4, 1.0f);
    __syncthreads();
    for (int i = tid; i < 3840; i += 1024) {
        int r = i / 60, c = i - r * 60;
        d2H[i] = HB[r * ST + c];
        d2L[i] = LA[r * ST + c];
    }
}

// ---------------- Kernel B: per-item chain (64 items/block, 16 waves, interleaved H+L;
// momentum update fused in when m != 1 — A matrices never leave LDS) ----------------
__global__ __launch_bounds__(1024) void chain_kernel(
    const float* __restrict__ spH, const float* __restrict__ spL,
    const float* __restrict__ dptH, const float* __restrict__ dptL,
    const float* __restrict__ d2H, const float* __restrict__ d2L,
    const float* __restrict__ w1_1, const float* __restrict__ b1_1,
    const float* __restrict__ w1_2, const float* __restrict__ b1_2,
    const float* __restrict__ w2_1, const float* __restrict__ b2_1,
    const float* __restrict__ w2_2, const float* __restrict__ b2_2,
    const float* __restrict__ wa1, const float* __restrict__ ba1,
    const float* __restrict__ wo1, const float* __restrict__ bo1,
    const float* __restrict__ wo2, const float* __restrict__ bo2,
    const int* __restrict__ mI,
    float* __restrict__ out)
{
    __shared__ __align__(16) float HA[64 * ST];
    __shared__ __align__(16) float HB[64 * ST];
    __shared__ __align__(16) float LA[64 * ST];
    __shared__ __align__(16) float LB[64 * ST];
    __shared__ float XLs[64];
    __shared__ float PH[16 * 64], PL[16 * 64];
    __shared__ float INVH[64], INVL[64];

    const int tid = threadIdx.x;
    const int w = __builtin_amdgcn_readfirstlane(tid >> 6);
    const int l = tid & 63;
    const int b0 = blockIdx.x * 64;
    const int b = b0 + l;
    const float mf = (float)(*mI);

    {
        int r = tid >> 4, q = tid & 15;
        *(float4*)(HA + r * ST + 4 * q) = ((const float4*)(spH + (size_t)b0 * 64))[tid];
        if (tid < 64) XLs[tid] = spL[b0 + tid];
    }
    __syncthreads();

    // s1: H 63->45 ; L 1->15
    dlayer4<63, 63, 3>(w1_1, b1_1, HA + l * ST, HB + l * ST, 45, w * 3, 1.0f);
    dlayer4<1, 1, 1>(w2_1, b2_1, XLs + l, LA + l * ST, 15, w, 1.0f);
    __syncthreads();
    // s2: H 45->30 ; L 15->30
    dlayer4<45, 45, 2>(w1_2, b1_2, HB + l * ST, HA + l * ST, 30, w * 2, 1.0f);
    dlayer4<15, 15, 2>(w2_2, b2_2, LA + l * ST, LB + l * ST, 30, w * 2, 1.0f);
    __syncthreads();
    // data copies + s3: 30->60 (wa1) both branches
    for (int i = tid; i < 1920; i += 1024) {
        int r = i / 30, c = i - r * 30;
        out[(size_t)b0 * 30 + i] = HA[r * ST + c];
        out[OFF1 + (size_t)b0 * 30 + i] = LB[r * ST + c];
    }
    dlayer4<30, 30, 4>(wa1, ba1, HA + l * ST, HB + l * ST, 60, w * 4, 1.0f);
    dlayer4<30, 30, 4>(wa1, ba1, LB + l * ST, LA + l * ST, 60, w * 4, 1.0f);
    __syncthreads();
    // s4: S = H1 @ D2^T (60->64) both branches
    dlayer4<60, 60, 4>(d2H, nullptr, HB + l * ST, HA + l * ST, 64, w * 4, 1.0f);
    dlayer4<60, 60, 4>(d2L, nullptr, LA + l * ST, LB + l * ST, 64, w * 4, 1.0f);
    __syncthreads();
    // s5: exp(S - max) both branches
    softmax_exp4(HA + l * ST, HB + l * ST, PH, w, l);
    softmax_exp4(LB + l * ST, LA + l * ST, PL, w, l);
    __syncthreads();
    // fused momentum update (only when m != 1): Dn += (1-m) * data^T @ A.
    // A = exp/sum lives in HB (H) / LA (L); data re-read from this block's own
    // out writes (ordered by the barriers above). mf is block-uniform -> the
    // inner __syncthreads is reached by all threads or none.
    if (mf != 1.0f) {
        if (tid < 64) INVH[tid] = inv16(PH, tid);
        else if (tid < 128) INVL[tid - 64] = inv16(PL, tid - 64);
        __syncthreads();
        const bool isH = w < 8;
        const float* E = isH ? HB : LA;
        const float* INV = isH ? INVH : INVL;
        const float* dat = out + (isH ? 0 : OFF1) + (size_t)b0 * 30;
        float* D = out + (isH ? OFF3 : OFF5);
        const int c0 = (w & 7) * 4;
        float acc[4];
#pragma unroll
        for (int k = 0; k < 4; ++k) acc[k] = 0.f;
        for (int it = 0; it < 64; ++it) {
            const float a = E[it * ST + l] * INV[it];
#pragma unroll
            for (int k = 0; k < 4; ++k) {
                int c = c0 + k; c = c < 30 ? c : 29;
                acc[k] = fmaf(dat[it * 30 + c], a, acc[k]);
            }
        }
        const float s = 1.0f - mf;
#pragma unroll
        for (int k = 0; k < 4; ++k) {
            int c = c0 + k;
            if (c < 30) atomicAdd(&D[c * 64 + l], s * acc[k]);
        }
    }
    {
        const float invH = inv16(PH, l);
        const float invL = inv16(PL, l);
        dlayerT4<64, 30, 2>(dptH, HB + l * ST, HA + l * ST, 30, w * 2, invH);
        dlayerT4<64, 30, 2>(dptL, LA + l * ST, LB + l * ST, 30, w * 2, invL);
    }
    __syncthreads();
    // s8: 30->60 (wa1) both branches
    dlayer4<30, 30, 4>(wa1, ba1, HA + l * ST, HB + l * ST, 60, w * 4, 1.0f);
    dlayer4<30, 30, 4>(wa1, ba1, LB + l * ST, LA + l * ST, 60, w * 4, 1.0f);
    __syncthreads();
    // HSI_A / LiDAR_A copies
    for (int i = tid; i < 3840; i += 1024) {
        int r = i / 60, c = i - r * 60;
        out[OFF2 + (size_t)b0 * 60 + i] = HB[r * ST + c];
        out[OFF4 + (size_t)b0 * 60 + i] = LA[r * ST + c];
    }
    // o1: 120->60 = wo1[:, :60]@A60l + wo1[:, 60:]@A60h (f4 chunked)
    {
        const int o0 = w * 4;
        float acc[4];
#pragma unroll
    for (int k = 0; k < 4; ++k) acc[k] = (o0 + k < 60) ? bo1[o0 + k] : 0.0f;
#pragma unroll
        for (int c0 = 0; c0 < 60; c0 += 16) {
            const int CH = (60 - c0) < 16 ? (60 - c0) : 16;
            float x[16];
            if (CH == 16) load_chunk<16>(LA + l * ST + c0, x);
            else load_chunk<12>(LA + l * ST + c0, x);
#pragma unroll
            for (int k = 0; k < 4; ++k) {
                int oc = o0 + k; oc = oc < 60 ? oc : 59;
                const float* Wr = wo1 + oc * 120 + c0;
                float a = acc[k];
#pragma unroll
                for (int j = 0; j < 16; ++j) if (j < CH) a = fmaf(Wr[j], x[j], a);
                acc[k] = a;
            }
        }
#pragma unroll
        for (int c0 = 0; c0 < 60; c0 += 16) {
            const int CH = (60 - c0) < 16 ? (60 - c0) : 16;
            float x[16];
            if (CH == 16) load_chunk<16>(HB + l * ST + c0, x);
            else load_chunk<12>(HB + l * ST + c0, x);
#pragma unroll
            for (int k = 0; k < 4; ++k) {
                int oc = o0 + k; oc = oc < 60 ? oc : 59;
                const float* Wr = wo1 + oc * 120 + 60 + c0;
                float a = acc[k];
#pragma unroll
                for (int j = 0; j < 16; ++j) if (j < CH) a = fmaf(Wr[j], x[j], a);
                acc[k] = a;
            }
        }
        if (o0 < 60) {
            float4 av; av.x = acc[0]; av.y = acc[1]; av.z = acc[2]; av.w = acc[3];
            *((float4*)(HA + l * ST + o0)) = av;
        }
    }
    __syncthreads();
    // o2: 60->7 (waves 0-6)
    if (w < 7) {
        float a = bo2[w];
        const float* Wr = wo2 + w * 60;
#pragma unroll
        for (int c0 = 0; c0 < 60; c0 += 16) {
            const int CH = (60 - c0) < 16 ? (60 - c0) : 16;
            float x[16];
            if (CH == 16) load_chunk<16>(HA + l * ST + c0, x);
            else load_chunk<12>(HA + l * ST + c0, x);
#pragma unroll
            for (int j = 0; j < 16; ++j) if (j < CH) a = fmaf(Wr[c0 + j], x[j], a);
        }
        out[OFF6 + (size_t)b * 7 + w] = a;
    }
}

extern "C" void kernel_launch(void* const* d_in, const int* in_sizes, int n_in,
                              void* d_out, int out_size, void* d_ws, size_t ws_size,
                              hipStream_t stream) {
    const float* H_HSI        = (const float*)d_in[0];
    const float* H_LiDAR      = (const float*)d_in[1];
    const float* HSI_D        = (const float*)d_in[2];
    const float* LiDAR_D      = (const float*)d_in[3];
    const float* Patch_HSI    = (const float*)d_in[4];
    const float* Patch_LiDAR  = (const float*)d_in[5];
    const float* D_Patch_HSI  = (const float*)d_in[6];
    const float* D_Patch_LiDAR= (const float*)d_in[7];
    const int*   mI           = (const int*)d_in[9];
    const float* w1_1 = (const float*)d_in[12];
    const float* b1_1 = (const float*)d_in[13];
    const float* w1_2 = (const float*)d_in[14];
    const float* b1_2 = (const float*)d_in[15];
    const float* w2_1 = (const float*)d_in[16];
    const float* b2_1 = (const float*)d_in[17];
    const float* w2_2 = (const float*)d_in[18];
    const float* b2_2 = (const float*)d_in[19];
    const float* wa1  = (const float*)d_in[20];
    const float* ba1  = (const float*)d_in[21];
    const float* wa2  = (const float*)d_in[22];
    const float* ba2  = (const float*)d_in[23];
    const float* wo1  = (const float*)d_in[24];
    const float* bo1  = (const float*)d_in[25];
    const float* wo2  = (const float*)d_in[26];
    const float* bo2  = (const float*)d_in[27];

    float* out = (float*)d_out;
    float* ws  = (float*)d_ws;

    patch_attend_kernel<<<NB / 4 + DN / 4, 256, 0, stream>>>(
        Patch_HSI, H_HSI, Patch_LiDAR, H_LiDAR, ws + SPH_OFF, ws + SPL_OFF,
        D_Patch_HSI, HSI_D, D_Patch_LiDAR, LiDAR_D, ws + DSPH_OFF, ws + DSPL_OFF);
    dict_chain_kernel<<<1, 1024, 0, stream>>>(
        ws + DSPH_OFF, ws + DSPL_OFF,
        w1_1, b1_1, w1_2, b1_2, w2_1, b2_1, w2_2, b2_2, wa2, ba2,
        ws + DPTH_OFF, ws + DPTL_OFF, ws + D2H_OFF, ws + D2L_OFF, mI, out);
    chain_kernel<<<NB / 64, 1024, 0, stream>>>(
        ws + SPH_OFF, ws + SPL_OFF,
        ws + DPTH_OFF, ws + DPTL_OFF, ws + D2H_OFF, ws + D2L_OFF,
        w1_1, b1_1, w1_2, b1_2, w2_1, b2_1, w2_2, b2_2,
        wa1, ba1, wo1, bo1, wo2, bo2, mI, out);
}